// Round 11
// baseline (96.732 us; speedup 1.0000x reference)
//
#include <hip/hip_runtime.h>
#include <stdint.h>

// Problem constants: IMG=512, CUT_SIZE=224, CUTN=64, B=4, C=3; sizes in [224,511]
constexpr int S   = 224;
constexpr int Wim = 512;
constexpr int Him = 512;
constexpr int PLANES = 12;                   // B*C
constexpr int N   = 64;
constexpr int SB  = 16;                      // source rows per band
constexpr int NBANDS = Him / SB;             // 32
constexpr int NGRP = 8;                      // cutouts per block
constexpr int GROUPS = N / NGRP;             // 8
constexpr int TILES = PLANES * NBANDS;       // 384 (plane,band) tiles
constexpr int TPX   = TILES / 8;             // 48 tiles per XCD
constexpr int GRID  = TILES * GROUPS;        // 3072 -> 12 blocks/CU, 4 co-resident
constexpr int ROWF  = 516;                   // LDS row stride (512 + zeroed pad)

__device__ __forceinline__ void load_lds16(const float* g, float* l) {
    __builtin_amdgcn_global_load_lds(
        (const __attribute__((address_space(1))) void*)g,
        (__attribute__((address_space(3))) void*)l, 16, 0, 0);
}

// iy0 exactly as reference computes it
__device__ __forceinline__ int iy0_of(int i, float scale, int sz) {
    const float sy = fmaxf(scale * ((float)i + 0.5f) - 0.5f, 0.0f);
    return min((int)floorf(sy), sz - 1);
}
// smallest i in [0,224] with iy0_of(i) >= P (exact predicate; proven in R4)
__device__ __forceinline__ int first_ge(float scale, int sz, int P) {
    if (P <= 0) return 0;
    if (P > sz - 1) return S;
    float c = ((float)P + 0.5f) / scale - 0.5f;
    int i = (int)ceilf(fminf(fmaxf(c, 0.0f), (float)S));
    while (i > 0 && iy0_of(i - 1, scale, sz) >= P) --i;
    while (i < S && iy0_of(i, scale, sz) < P) ++i;
    return i;
}

__global__ __launch_bounds__(512) void cutouts_kernel(
    const float* __restrict__ x,
    const int*   __restrict__ sizes,
    const int*   __restrict__ offx,
    const int*   __restrict__ offy,
    float*       __restrict__ out)
{
    __shared__ float lds[SB + 1][ROWF];      // 35,088 B -> 4 blocks/CU

    const int lane = threadIdx.x & 63;
    const int wv   = threadIdx.x >> 6;       // 0..7

    // decode: XCD-affine (plane,band) tile; 8 consecutive locals share a tile (L2 reuse)
    const int xcd   = blockIdx.x & 7;
    const int local = blockIdx.x >> 3;       // 0..383
    const int tk    = local >> 3;            // tile-in-xcd 0..47
    const int g     = local & 7;             // cutout group 0..7
    const int t     = xcd * TPX + tk;        // 0..383
    const int pi    = t >> 5;                // plane 0..11
    const int b     = t & 31;                // band 0..31

    // zero pad cols [512..515] (hit only by weight-0 neighbor reads)
    if (threadIdx.x < (SB + 1) * 4)
        lds[threadIdx.x >> 2][Wim + (threadIdx.x & 3)] = 0.0f;

    // stage band once: 17 rows x 512 floats = 34 chunks of 1 KB DMA
    const float* plane = x + (size_t)pi * (Him * Wim);
    for (int c = wv; c < (SB + 1) * 2; c += 8) {
        const int row  = c >> 1, half = c & 1;
        const int srow = min(SB * b + row, Him - 1);   // band 31 row16 dup (wt-0 only)
        load_lds16(plane + (size_t)srow * Wim + half * 256 + lane * 4,
                   &lds[row][half * 256]);
    }
    asm volatile("s_waitcnt vmcnt(0)" ::: "memory");
    __syncthreads();

    #pragma unroll 1
    for (int nn = 0; nn < NGRP; ++nn) {
        const int n  = g * NGRP + nn;
        const int sz = sizes[n];
        const int oy = offy[n];
        const int ox = offx[n];
        const float scale = (float)sz / (float)S;

        const int L    = SB * b - oy;                  // band range rel. to cutout
        const int i_lo = first_ge(scale, sz, L);       // bands partition [0,224)
        const int i_hi = first_ge(scale, sz, L + SB);
        if (i_lo >= i_hi) continue;

        // horizontal params once per cutout (reused for all its rows)
        int dv[4]; float fxv[4];
        #pragma unroll
        for (int r = 0; r < 4; ++r) {
            const int   px = r * 64 + lane;
            const float sx = fmaxf(scale * ((float)px + 0.5f) - 0.5f, 0.0f);
            const float fi = floorf(sx);
            fxv[r] = sx - fi;                          // ix0 <= sz-1 (proven, sz>=224)
            dv[r]  = ox + (int)fi;                     // d+1 <= 512: pad col zeroed
        }

        float* oplane = out + (size_t)(n * PLANES + pi) * (S * S);

        for (int i = i_lo + wv; i < i_hi; i += 8) {
            const float sy  = fmaxf(scale * ((float)i + 0.5f) - 0.5f, 0.0f);
            const float fiy = floorf(sy);
            const float fy  = sy - fiy;                // frac BEFORE clamp (reference)
            const int   rel = (int)fiy - L;            // in [0, 15]
            const float* l0 = &lds[rel][0];
            const float* l1 = &lds[rel + 1][0];        // rel+1 <= 16 staged
            float* orow = oplane + (size_t)i * S;

            #pragma unroll
            for (int r = 0; r < 4; ++r) {
                if (r < 3 || lane < 32) {              // 224 = 3*64 + 32
                    const int   d = dv[r];
                    const float f = fxv[r];
                    const float a0 = l0[d], a1 = l0[d + 1];
                    const float c0 = l1[d], c1 = l1[d + 1];
                    const float top = a0 + (a1 - a0) * f;
                    const float bot = c0 + (c1 - c0) * f;
                    orow[r * 64 + lane] = top + (bot - top) * fy;
                }
            }
        }
    }
}

extern "C" void kernel_launch(void* const* d_in, const int* in_sizes, int n_in,
                              void* d_out, int out_size, void* d_ws, size_t ws_size,
                              hipStream_t stream) {
    const float* x     = (const float*)d_in[0];
    const int*   sizes = (const int*)d_in[1];
    const int*   offx  = (const int*)d_in[2];
    const int*   offy  = (const int*)d_in[3];
    float* out = (float*)d_out;

    cutouts_kernel<<<GRID, 512, 0, stream>>>(x, sizes, offx, offy, out);
}

// Round 12
// 39.481 us; speedup vs baseline: 2.4501x; 2.4501x over previous
//
#include <hip/hip_runtime.h>
#include <stdint.h>

// Problem constants: IMG=512, CUT_SIZE=224, CUTN=64, B=4, C=3; sizes in [224,511]
constexpr int S   = 224;
constexpr int Wim = 512;
constexpr int Him = 512;
constexpr int PLANES = 12;                   // B*C
constexpr int N   = 64;
constexpr int SB  = 16;                      // source rows per band
constexpr int NBANDS = Him / SB;             // 32
constexpr int NGRP = 8;                      // cutouts per block
constexpr int GROUPS = N / NGRP;             // 8
constexpr int TILES = PLANES * NBANDS;       // 384 (plane,band) tiles
constexpr int TPX   = TILES / 8;             // 48 tiles per XCD
constexpr int WPB   = 4;                     // 256 threads
constexpr int GRID  = TILES * GROUPS;        // 3072
constexpr int ROWF  = 516;                   // LDS row stride (512 + zeroed pad)

__device__ __forceinline__ void load_lds16(const float* g, float* l) {
    __builtin_amdgcn_global_load_lds(
        (const __attribute__((address_space(1))) void*)g,
        (__attribute__((address_space(3))) void*)l, 16, 0, 0);
}

// iy0 exactly as reference computes it
__device__ __forceinline__ int iy0_of(int i, float scale, int sz) {
    const float sy = fmaxf(scale * ((float)i + 0.5f) - 0.5f, 0.0f);
    return min((int)floorf(sy), sz - 1);
}

__global__ __launch_bounds__(256) void cutouts_kernel(
    const float* __restrict__ x,
    const int*   __restrict__ sizes,
    const int*   __restrict__ offx,
    const int*   __restrict__ offy,
    float*       __restrict__ out)
{
    __shared__ float lds[SB + 1][ROWF];      // 35,088 B -> 4 blocks/CU, 16 waves

    const int lane = threadIdx.x & 63;
    const int wv   = threadIdx.x >> 6;       // 0..3

    // decode: XCD-affine (plane,band) tile; 8 consecutive locals share a tile
    const int xcd   = blockIdx.x & 7;
    const int local = blockIdx.x >> 3;       // 0..383
    const int tk    = local >> 3;            // tile-in-xcd 0..47
    const int g     = local & 7;             // cutout group 0..7
    const int t     = xcd * TPX + tk;        // 0..383
    const int pi    = t >> 5;                // plane 0..11
    const int b     = t & 31;                // band 0..31

    // zero pad cols [512..515] (hit only by weight-0 neighbor reads)
    if (threadIdx.x < (SB + 1) * 4)
        lds[threadIdx.x >> 2][Wim + (threadIdx.x & 3)] = 0.0f;

    // stage band once: 17 rows x 512 floats = 34 chunks of 1 KB DMA
    const float* plane = x + (size_t)pi * (Him * Wim);
    for (int c = wv; c < (SB + 1) * 2; c += WPB) {
        const int row  = c >> 1, half = c & 1;
        const int srow = min(SB * b + row, Him - 1);   // dup row (wt-0 only)
        load_lds16(plane + (size_t)srow * Wim + half * 256 + lane * 4,
                   &lds[row][half * 256]);
    }

    // in-lane parallel first_ge: lane c<8 -> i_lo(cutout c); lanes 8..15 -> i_hi.
    // ONE first_ge execution per wave (R11 paid 16 per wave). Lanes 16-63
    // duplicate lanes 0-15's work (same convergence, no extra cost).
    int flv;
    {
        const int   idx = lane & 7;
        const int   nn_ = g * NGRP + idx;
        const int   szl = sizes[nn_];
        const int   oyl = offy[nn_];
        const float scl = (float)szl / (float)S;
        const int   P   = SB * b - oyl + ((lane & 8) ? SB : 0);
        int res;
        if (P <= 0) res = 0;
        else if (P > szl - 1) res = S;
        else {
            const float cc = ((float)P + 0.5f) / scl - 0.5f;
            int i = (int)ceilf(fminf(fmaxf(cc, 0.0f), (float)S));
            while (i > 0 && iy0_of(i - 1, scl, szl) >= P) --i;
            while (i < S && iy0_of(i, scl, szl) < P) ++i;
            res = i;
        }
        flv = res;
    }

    asm volatile("s_waitcnt vmcnt(0)" ::: "memory");
    __syncthreads();

    #pragma unroll 1
    for (int nn = 0; nn < NGRP; ++nn) {
        const int i_lo = __builtin_amdgcn_readlane(flv, nn);      // SGPR, uniform
        const int i_hi = __builtin_amdgcn_readlane(flv, nn + 8);
        if (i_lo >= i_hi) continue;                               // scalar branch

        const int n  = g * NGRP + nn;
        const int sz = sizes[n];
        const int oy = offy[n];
        const int ox = offx[n];
        const float scale = (float)sz / (float)S;
        const int   L     = SB * b - oy;

        // horizontal params once per (wave,cutout), reused for all its rows
        int dv[4]; float fxv[4];
        #pragma unroll
        for (int r = 0; r < 4; ++r) {
            const int   px = r * 64 + lane;
            const float sx = fmaxf(scale * ((float)px + 0.5f) - 0.5f, 0.0f);
            const float fi = floorf(sx);
            fxv[r] = sx - fi;                          // ix0 <= sz-1 (sz>=224)
            dv[r]  = ox + (int)fi;                     // d+1 <= 512: pad zeroed
        }

        float* oplane = out + (size_t)(n * PLANES + pi) * (S * S);

        for (int i = i_lo + wv; i < i_hi; i += WPB) {
            const float sy  = fmaxf(scale * ((float)i + 0.5f) - 0.5f, 0.0f);
            const float fiy = floorf(sy);
            const float fy  = sy - fiy;                // frac BEFORE clamp
            const int   rel = (int)fiy - L;            // in [0,15] (partition proof)
            const float* l0 = &lds[rel][0];
            const float* l1 = &lds[rel + 1][0];        // rel+1 <= 16 staged
            float* orow = oplane + (size_t)i * S;

            #pragma unroll
            for (int r = 0; r < 4; ++r) {
                if (r < 3 || lane < 32) {              // 224 = 3*64 + 32
                    const int   d = dv[r];
                    const float f = fxv[r];
                    const float a0 = l0[d], a1 = l0[d + 1];   // ds_read2_b32
                    const float c0 = l1[d], c1 = l1[d + 1];
                    const float top = a0 + (a1 - a0) * f;
                    const float bot = c0 + (c1 - c0) * f;
                    orow[r * 64 + lane] = top + (bot - top) * fy;
                }
            }
        }
    }
}

extern "C" void kernel_launch(void* const* d_in, const int* in_sizes, int n_in,
                              void* d_out, int out_size, void* d_ws, size_t ws_size,
                              hipStream_t stream) {
    const float* x     = (const float*)d_in[0];
    const int*   sizes = (const int*)d_in[1];
    const int*   offx  = (const int*)d_in[2];
    const int*   offy  = (const int*)d_in[3];
    float* out = (float*)d_out;

    cutouts_kernel<<<GRID, 256, 0, stream>>>(x, sizes, offx, offy, out);
}